// Round 11
// baseline (448.435 us; speedup 1.0000x reference)
//
#include <hip/hip_runtime.h>
#include <hip/hip_bf16.h>

typedef unsigned short ushort_t;
typedef unsigned int uint_t;

#define DD   128
#define G4   512
#define BT   16
#define NB   128
#define NV   32

// param block offsets (floats), each section 256-aligned so prep blocks map 1:1 to sources
#define OFF_WIH   0
#define OFF_EB    16384
#define OFF_PW    32768
#define OFF_PB    36864
#define OFF_INW   37120
#define OFF_INB   86272
#define OFF_OUTW  86784
#define OFF_OUTB  103168
#define OFF_IHB   103424
#define OFF_ICB   107520
#define OFF_DBIH  111616
#define OFF_DBHH  128000
#define OFF_DOW   144384
#define OFF_DOB   148480
#define P_TOTAL   148736   // = 581 * 256
// dtype flags stashed in PB-section padding: [32]=X, [33]=eWhh, [34]=iHw, [35]=iCw, [36]=dWhh
#define OFF_FLAGS (OFF_PB + 32)

typedef __attribute__((ext_vector_type(8))) short bf16x8;
typedef __attribute__((ext_vector_type(4))) float f32x4;

__device__ __forceinline__ float bf2f(ushort_t u) {
    union { uint_t i; float f; } x; x.i = ((uint_t)u) << 16; return x.f;
}
__device__ __forceinline__ ushort_t f2bf(float f) {
    __hip_bfloat16 h = __float2bfloat16(f);   // RNE
    return *(ushort_t*)&h;
}
__device__ __forceinline__ float sigmoid_f(float x) {
    return __builtin_amdgcn_rcpf(1.f + __expf(-x));
}
__device__ __forceinline__ float tanh_f(float x) {
    float e = __expf(2.f * x);
    return 1.f - 2.f * __builtin_amdgcn_rcpf(e + 1.f);
}
__device__ __forceinline__ void store_out(void* out, long idx, float v, int bf) {
    if (bf) ((ushort_t*)out)[idx] = f2bf(v);
    else    ((float*)out)[idx]    = v;
}
// per-wave dtype probe: 1 if data looks bf16 when read as ushort
__device__ __forceinline__ int wave_probe(const void* p, int elems) {
    int cap = elems < 2048 ? elems : 2048;
    int lane = threadIdx.x & 63;
    const ushort_t* u = (const ushort_t*)p;
    int cnt = 0, tot = 0;
    for (int j = lane; j < cap; j += 64) {
        ushort_t x = u[j];
        float af = fabsf(bf2f(x));
        tot++;
        if (x == 0 || (af > 1e-7f && af < 100.f)) cnt++;
    }
    #pragma unroll
    for (int off = 32; off >= 1; off >>= 1) {
        cnt += __shfl_xor(cnt, off);
        tot += __shfl_xor(tot, off);
    }
    return (cnt * 10 >= tot * 9) ? 1 : 0;
}

struct Ptr19 { const void* p[19]; };

// ---------------- prep: params (581) + X transpose (256) + dtype flags (5) ----------------
__global__ __launch_bounds__(256) void prep_kernel(Ptr19 a, float* __restrict__ P,
                                                   float* __restrict__ Xc) {
    __shared__ float tile[32][65];
    if (blockIdx.x < 581) {
        int base = blockIdx.x * 256;
        int src, o0, size;
        if      (base < OFF_EB)   { src = 1;  o0 = base - OFF_WIH;  size = 16384; }
        else if (base < OFF_PW)   { src = 3;  o0 = base - OFF_EB;   size = 16384; }
        else if (base < OFF_PB)   { src = 4;  o0 = base - OFF_PW;   size = 4096;  }
        else if (base < OFF_INW)  { src = 5;  o0 = base - OFF_PB;   size = 32;    }
        else if (base < OFF_INB)  { src = 6;  o0 = base - OFF_INW;  size = 49152; }
        else if (base < OFF_OUTW) { src = 7;  o0 = base - OFF_INB;  size = 384;   }
        else if (base < OFF_OUTB) { src = 8;  o0 = base - OFF_OUTW; size = 16384; }
        else if (base < OFF_IHB)  { src = 9;  o0 = base - OFF_OUTB; size = 128;   }
        else if (base < OFF_ICB)  { src = 11; o0 = base - OFF_IHB;  size = 4096;  }
        else if (base < OFF_DBIH) { src = 13; o0 = base - OFF_ICB;  size = 4096;  }
        else if (base < OFF_DBHH) { src = 15; o0 = base - OFF_DBIH; size = 16384; }
        else if (base < OFF_DOW)  { src = 16; o0 = base - OFF_DBHH; size = 16384; }
        else if (base < OFF_DOB)  { src = 17; o0 = base - OFF_DOW;  size = 4096;  }
        else                      { src = 18; o0 = base - OFF_DOB;  size = 32;    }
        int bf = wave_probe(a.p[src], size);
        int off = o0 + (int)threadIdx.x;
        if (off < size)
            P[base + threadIdx.x] = bf ? bf2f(((const ushort_t*)a.p[src])[off])
                                       : ((const float*)a.p[src])[off];
    } else if (blockIdx.x < 837) {
        int bf = wave_probe(a.p[0], 2048);
        int idx2 = blockIdx.x - 581;
        int bt = (idx2 & 3) * 32, tn0 = (idx2 >> 2) * 64;
        const void* src = a.p[0];
        int tx = threadIdx.x & 63, ty = threadIdx.x >> 6;
        #pragma unroll
        for (int k = 0; k < 8; k++) {
            int row = ty * 8 + k;
            int idx = (bt + row) * 4096 + tn0 + tx;
            tile[row][tx] = bf ? bf2f(((const ushort_t*)src)[idx]) : ((const float*)src)[idx];
        }
        __syncthreads();
        int bx = threadIdx.x & 31, tyy = threadIdx.x >> 5;
        #pragma unroll
        for (int k = 0; k < 8; k++) {
            int tn = tn0 + tyy * 8 + k;
            int t = tn >> 5, nn = tn & 31;
            Xc[t * 4096 + nn * 128 + bt + bx] = tile[bx][tyy * 8 + k];
        }
    } else {
        int which = blockIdx.x - 837;            // 0..4
        int src = (which == 0) ? 0 : (which == 1) ? 2 : (which == 2) ? 10
                : (which == 3) ? 12 : 14;
        int flag = wave_probe(a.p[src], 2048);
        if (threadIdx.x == 0) P[OFF_FLAGS + which] = (float)flag;
    }
}

// ===================== encoder: operand-swapped MFMA recurrence, split chains =====================
// D[g-row][b-col]: thread owns (b = l15, d = 16w + 4quad + r, r=0..3).
__global__ __launch_bounds__(512, 2) void enc_kernel(
    const float* __restrict__ Xc, const void* __restrict__ Wraw,
    const float* __restrict__ P, float* __restrict__ Cout)
{
    const int n = blockIdx.y, b0 = blockIdx.x * BT;
    const int tid = threadIdx.x;
    const int w = tid >> 6, lane = tid & 63;
    const int l15 = lane & 15, quad = lane >> 4;
    const int wbf = P[OFF_FLAGS + 1] > 0.5f;
    const int bown = b0 + l15;

    __shared__ alignas(16) ushort_t hS[2][16 * 136];
    for (int i = tid; i < 16 * 136; i += 512) hS[0][i] = 0;

    // A-fragments (weights): lane holds W[g = typ*128 + 16w + l15][k = 32kc+8quad+j]
    bf16x8 afrag[4][4];
    #pragma unroll
    for (int typ = 0; typ < 4; typ++) {
        const int g = typ * 128 + 16 * w + l15;
        #pragma unroll
        for (int kc = 0; kc < 4; kc++) {
            const int base = (n * G4 + g) * DD + 32 * kc + 8 * quad;
            if (wbf) {
                afrag[typ][kc] = *(const bf16x8*)((const ushort_t*)Wraw + base);
            } else {
                const float* fp = (const float*)Wraw + base;
                bf16x8 tmp;
                #pragma unroll
                for (int j = 0; j < 8; j++) tmp[j] = (short)f2bf(fp[j]);
                afrag[typ][kc] = tmp;
            }
        }
    }

    // pool A-fragment: ALL rows carry pw -> every thread's accP[0] = s(bown), no broadcast needed
    bf16x8 pfrag[4];
    #pragma unroll
    for (int kc = 0; kc < 4; kc++) {
        bf16x8 tmp;
        #pragma unroll
        for (int j = 0; j < 8; j++)
            tmp[j] = (short)f2bf(P[OFF_PW + n * DD + 32 * kc + 8 * quad + j]);
        pfrag[kc] = tmp;
    }

    f32x4 bias4[4], wih4[4];
    #pragma unroll
    for (int typ = 0; typ < 4; typ++) {
        int base = n * G4 + typ * 128 + 16 * w + 4 * quad;
        bias4[typ] = *(const f32x4*)&P[OFF_EB + base];
        wih4[typ]  = *(const f32x4*)&P[OFF_WIH + base];
    }
    const float pb_r = P[OFF_PB + n];

    float cst[4], hprev[4], Cacc[4], lR = 0.f;
    #pragma unroll
    for (int r = 0; r < 4; r++) { cst[r] = 0.f; hprev[r] = 0.f; Cacc[r] = 0.f; }

    float xq = Xc[n * 128 + bown];   // t = 0

#define ENC_STEP(T, RB)                                                              \
    do {                                                                             \
        __syncthreads();                                                             \
        bf16x8 bh[4];                                                                \
        _Pragma("unroll")                                                            \
        for (int kc = 0; kc < 4; kc++)                                               \
            bh[kc] = *(const bf16x8*)&hS[RB][l15 * 136 + 32 * kc + 8 * quad];        \
        f32x4 acc[4], acc2[4], accP, accP2;                                          \
        _Pragma("unroll")                                                            \
        for (int typ = 0; typ < 4; typ++) {                                          \
            f32x4 a;                                                                 \
            a.x = bias4[typ].x + xq * wih4[typ].x;                                   \
            a.y = bias4[typ].y + xq * wih4[typ].y;                                   \
            a.z = bias4[typ].z + xq * wih4[typ].z;                                   \
            a.w = bias4[typ].w + xq * wih4[typ].w;                                   \
            acc[typ] = a;                                                            \
            acc2[typ].x = 0.f; acc2[typ].y = 0.f; acc2[typ].z = 0.f; acc2[typ].w = 0.f; \
        }                                                                            \
        accP.x = pb_r; accP.y = pb_r; accP.z = pb_r; accP.w = pb_r;                  \
        accP2.x = 0.f; accP2.y = 0.f; accP2.z = 0.f; accP2.w = 0.f;                  \
        if ((T) < 126) xq = Xc[((T) + 1) * 4096 + n * 128 + bown];                   \
        _Pragma("unroll")                                                            \
        for (int kc = 0; kc < 2; kc++) {                                             \
            accP = __builtin_amdgcn_mfma_f32_16x16x32_bf16(pfrag[kc], bh[kc], accP, 0, 0, 0); \
            _Pragma("unroll")                                                        \
            for (int typ = 0; typ < 4; typ++)                                        \
                acc[typ] = __builtin_amdgcn_mfma_f32_16x16x32_bf16(afrag[typ][kc], bh[kc], acc[typ], 0, 0, 0); \
        }                                                                            \
        _Pragma("unroll")                                                            \
        for (int kc = 2; kc < 4; kc++) {                                             \
            accP2 = __builtin_amdgcn_mfma_f32_16x16x32_bf16(pfrag[kc], bh[kc], accP2, 0, 0, 0); \
            _Pragma("unroll")                                                        \
            for (int typ = 0; typ < 4; typ++)                                        \
                acc2[typ] = __builtin_amdgcn_mfma_f32_16x16x32_bf16(afrag[typ][kc], bh[kc], acc2[typ], 0, 0, 0); \
        }                                                                            \
        _Pragma("unroll")                                                            \
        for (int typ = 0; typ < 4; typ++) acc[typ] = acc[typ] + acc2[typ];           \
        if ((T) > 0) {                                                               \
            float e = __expf(accP[0] + accP2[0]);                                    \
            lR += e;                                                                 \
            _Pragma("unroll")                                                        \
            for (int r = 0; r < 4; r++) Cacc[r] = fmaf(e, hprev[r], Cacc[r]);        \
        }                                                                            \
        ushort4 hw;                                                                  \
        _Pragma("unroll")                                                            \
        for (int r = 0; r < 4; r++) {                                                \
            float ii = sigmoid_f(acc[0][r]);                                         \
            float ff = sigmoid_f(acc[1][r]);                                         \
            float g2 = tanh_f(acc[2][r]);                                            \
            float oo = sigmoid_f(acc[3][r]);                                         \
            float cc = ff * cst[r] + ii * g2;                                        \
            cst[r] = cc;                                                             \
            float hh = oo * tanh_f(cc);                                              \
            hprev[r] = hh;                                                           \
            ((ushort_t*)&hw)[r] = f2bf(hh);                                          \
        }                                                                            \
        *(ushort4*)&hS[(RB) ^ 1][l15 * 136 + 16 * w + 4 * quad] = hw;                \
    } while (0)

    for (int tp = 0; tp < 63; tp++) {
        ENC_STEP(2 * tp, 0);
        ENC_STEP(2 * tp + 1, 1);
    }
    ENC_STEP(126, 0);
#undef ENC_STEP

    // final fold: score of h_126 (in hS[1])
    __syncthreads();
    {
        f32x4 accP;
        accP.x = pb_r; accP.y = pb_r; accP.z = pb_r; accP.w = pb_r;
        #pragma unroll
        for (int kc = 0; kc < 4; kc++) {
            bf16x8 bh = *(const bf16x8*)&hS[1][l15 * 136 + 32 * kc + 8 * quad];
            accP = __builtin_amdgcn_mfma_f32_16x16x32_bf16(pfrag[kc], bh, accP, 0, 0, 0);
        }
        float e = __expf(accP[0]);
        lR += e;
        #pragma unroll
        for (int r = 0; r < 4; r++) Cacc[r] = fmaf(e, hprev[r], Cacc[r]);
    }
    float inv = 1.f / lR;
    f32x4 cv;
    cv.x = Cacc[0] * inv; cv.y = Cacc[1] * inv; cv.z = Cacc[2] * inv; cv.w = Cacc[3] * inv;
    *(f32x4*)&Cout[bown * (NV * DD) + n * DD + 16 * w + 4 * quad] = cv;
}

// ---------------- QKV projection ----------------
__global__ __launch_bounds__(256) void qkv_kernel(
    const float* __restrict__ C, const float* __restrict__ P,
    float* __restrict__ q, float* __restrict__ k, float* __restrict__ v)
{
    int b = blockIdx.x, p = blockIdx.y, tid = threadIdx.x;
    int j = tid & 127, half = tid >> 7;
    __shared__ float Cb[NV * DD];
    for (int i = tid; i < NV * DD; i += 256) Cb[i] = C[b * (NV * DD) + i];
    __syncthreads();

    const float* wrow = P + OFF_INW + (p * DD + j) * DD;
    float bias = P[OFF_INB + p * DD + j];
    float acc[16];
    #pragma unroll
    for (int nn = 0; nn < 16; nn++) acc[nn] = bias;

    for (int dc = 0; dc < DD; dc += 8) {
        float4 w0 = *(const float4*)&wrow[dc];
        float4 w1 = *(const float4*)&wrow[dc + 4];
        #pragma unroll
        for (int nn = 0; nn < 16; nn++) {
            const float* cb = &Cb[(half * 16 + nn) * DD + dc];
            float4 c0 = *(float4*)&cb[0];
            float4 c1 = *(float4*)&cb[4];
            acc[nn] += c0.x * w0.x + c0.y * w0.y + c0.z * w0.z + c0.w * w0.w
                     + c1.x * w1.x + c1.y * w1.y + c1.z * w1.z + c1.w * w1.w;
        }
    }
    float* dst = (p == 0) ? q : (p == 1) ? k : v;
    for (int nn = 0; nn < 16; nn++)
        dst[b * (NV * DD) + (half * 16 + nn) * DD + j] = acc[nn];
}

// ---------------- cross-attention + out-proj + residual ----------------
__global__ __launch_bounds__(256) void attn_kernel(
    const float* __restrict__ q, const float* __restrict__ k, const float* __restrict__ v,
    const float* __restrict__ C, const float* __restrict__ P,
    float* __restrict__ Cstar, void* __restrict__ dout)
{
    int b = blockIdx.x, tid = threadIdx.x;
    int obf = P[OFF_FLAGS + 0] > 0.5f;
    __shared__ float Qs[NV * DD], Ks[NV * DD], Vs[NV * DD];
    float* Os = Ks;
    for (int i = tid; i < NV * DD; i += 256) Qs[i] = q[b * (NV * DD) + i];
    __syncthreads();

    int hh = tid >> 5, qi = tid & 31;
    float qreg[16];
    #pragma unroll
    for (int u = 0; u < 4; u++) {
        float4 t4 = *(float4*)&Qs[qi * DD + hh * 16 + 4 * u];
        qreg[4*u] = t4.x; qreg[4*u+1] = t4.y; qreg[4*u+2] = t4.z; qreg[4*u+3] = t4.w;
    }

    float Oacc[16];
    #pragma unroll
    for (int u = 0; u < 16; u++) Oacc[u] = 0.f;
    float wsum = 0.f;
    int tmax = (b < 5) ? b : 5;

    for (int tau = 1; tau <= tmax; tau++) {
        __syncthreads();
        for (int i = tid; i < NV * DD; i += 256) {
            Ks[i] = k[(b - tau) * (NV * DD) + i];
            Vs[i] = v[(b - tau) * (NV * DD) + i];
        }
        __syncthreads();

        float s[NV];
        #pragma unroll
        for (int kk = 0; kk < NV; kk++) {
            float a = 0.f;
            #pragma unroll
            for (int u = 0; u < 4; u++) {
                float4 kv = *(float4*)&Ks[kk * DD + hh * 16 + 4 * u];
                a += qreg[4*u] * kv.x + qreg[4*u+1] * kv.y
                   + qreg[4*u+2] * kv.z + qreg[4*u+3] * kv.w;
            }
            s[kk] = a * 0.25f;
        }
        float mm = s[0];
        #pragma unroll
        for (int kk = 1; kk < NV; kk++) mm = fmaxf(mm, s[kk]);
        float ssum = 0.f;
        #pragma unroll
        for (int kk = 0; kk < NV; kk++) { s[kk] = __expf(s[kk] - mm); ssum += s[kk]; }
        float wdk = __expf(-0.7f * (float)(tau - 1));
        wsum += wdk;
        float wr = wdk / ssum;
        #pragma unroll
        for (int u = 0; u < 4; u++) {
            float ax = 0.f, ay = 0.f, az = 0.f, aw = 0.f;
            #pragma unroll
            for (int kk = 0; kk < NV; kk++) {
                float4 vv = *(float4*)&Vs[kk * DD + hh * 16 + 4 * u];
                ax += s[kk] * vv.x; ay += s[kk] * vv.y;
                az += s[kk] * vv.z; aw += s[kk] * vv.w;
            }
            Oacc[4*u] += wr * ax; Oacc[4*u+1] += wr * ay;
            Oacc[4*u+2] += wr * az; Oacc[4*u+3] += wr * aw;
        }
    }

    __syncthreads();
    float winv = (b > 0) ? 1.f / wsum : 0.f;
    #pragma unroll
    for (int u = 0; u < 16; u++)
        Os[qi * DD + hh * 16 + u] = Oacc[u] * winv;
    __syncthreads();

    int j = tid & 127, ng = tid >> 7;
    const float* wrow = P + OFF_OUTW + j * DD;
    float obias = P[OFF_OUTB + j];
    for (int nn = ng * 16; nn < ng * 16 + 16; nn++) {
        float a = (b > 0) ? obias : 0.f;
        for (int dc = 0; dc < DD; dc += 8) {
            float4 w0 = *(const float4*)&wrow[dc];
            float4 w1 = *(const float4*)&wrow[dc + 4];
            float4 o0 = *(float4*)&Os[nn * DD + dc];
            float4 o1 = *(float4*)&Os[nn * DD + dc + 4];
            a += o0.x*w0.x + o0.y*w0.y + o0.z*w0.z + o0.w*w0.w
               + o1.x*w1.x + o1.y*w1.y + o1.z*w1.z + o1.w*w1.w;
        }
        float cs = C[b * (NV * DD) + nn * DD + j] + a;
        Cstar[b * (NV * DD) + nn * DD + j] = cs;
        store_out(dout, 524288 + b * (NV * DD) + nn * DD + j, cs, obf);
    }
}

// ===================== decoder: fused init + MFMA recurrence, split chains =====================
__global__ __launch_bounds__(512, 2) void dec_kernel(
    const float* __restrict__ Cstar,
    const void* __restrict__ iHw, const void* __restrict__ iCw,
    const void* __restrict__ Wraw,
    const float* __restrict__ P, void* __restrict__ out)
{
    const int n = blockIdx.y, b0 = blockIdx.x * BT;
    const int tid = threadIdx.x;
    const int w = tid >> 6, lane = tid & 63;
    const int l15 = lane & 15, quad = lane >> 4;
    const int obf = P[OFF_FLAGS + 0] > 0.5f;
    const int hbf = P[OFF_FLAGS + 2] > 0.5f;
    const int cbf = P[OFF_FLAGS + 3] > 0.5f;
    const int wbf = P[OFF_FLAGS + 4] > 0.5f;
    const int bown = b0 + l15;

    __shared__ alignas(16) ushort_t hS[2][16 * 136];

    // ---- fused init: D[e-row][b-col] = Cst·W^T + b ----
    bf16x8 cstB[4];
    #pragma unroll
    for (int kc = 0; kc < 4; kc++) {
        const float* cp = &Cstar[bown * (NV * DD) + n * DD + 32 * kc + 8 * quad];
        f32x4 c0v = *(const f32x4*)&cp[0];
        f32x4 c1v = *(const f32x4*)&cp[4];
        bf16x8 tmp;
        tmp[0] = (short)f2bf(c0v.x); tmp[1] = (short)f2bf(c0v.y);
        tmp[2] = (short)f2bf(c0v.z); tmp[3] = (short)f2bf(c0v.w);
        tmp[4] = (short)f2bf(c1v.x); tmp[5] = (short)f2bf(c1v.y);
        tmp[6] = (short)f2bf(c1v.z); tmp[7] = (short)f2bf(c1v.w);
        cstB[kc] = tmp;
    }
    float cst[4];
    {
        f32x4 hAcc = *(const f32x4*)&P[OFF_IHB + n * DD + 16 * w + 4 * quad];
        f32x4 cAcc = *(const f32x4*)&P[OFF_ICB + n * DD + 16 * w + 4 * quad];
        #pragma unroll
        for (int kc = 0; kc < 4; kc++) {
            const int base = (n * DD + 16 * w + l15) * DD + 32 * kc + 8 * quad;
            bf16x8 wA;
            if (hbf) wA = *(const bf16x8*)((const ushort_t*)iHw + base);
            else {
                const float* fp = (const float*)iHw + base;
                #pragma unroll
                for (int j = 0; j < 8; j++) wA[j] = (short)f2bf(fp[j]);
            }
            hAcc = __builtin_amdgcn_mfma_f32_16x16x32_bf16(wA, cstB[kc], hAcc, 0, 0, 0);
            if (cbf) wA = *(const bf16x8*)((const ushort_t*)iCw + base);
            else {
                const float* fp = (const float*)iCw + base;
                #pragma unroll
                for (int j = 0; j < 8; j++) wA[j] = (short)f2bf(fp[j]);
            }
            cAcc = __builtin_amdgcn_mfma_f32_16x16x32_bf16(wA, cstB[kc], cAcc, 0, 0, 0);
        }
        ushort4 hw;
        #pragma unroll
        for (int r = 0; r < 4; r++) {
            ((ushort_t*)&hw)[r] = f2bf(tanh_f(hAcc[r]));
            cst[r] = tanh_f(cAcc[r]);
        }
        *(ushort4*)&hS[0][l15 * 136 + 16 * w + 4 * quad] = hw;
    }

    // ---- recurrence weights (A-operand) ----
    bf16x8 afrag[4][4];
    #pragma unroll
    for (int typ = 0; typ < 4; typ++) {
        const int g = typ * 128 + 16 * w + l15;
        #pragma unroll
        for (int kc = 0; kc < 4; kc++) {
            const int base = (n * G4 + g) * DD + 32 * kc + 8 * quad;
            if (wbf) {
                afrag[typ][kc] = *(const bf16x8*)((const ushort_t*)Wraw + base);
            } else {
                const float* fp = (const float*)Wraw + base;
                bf16x8 tmp;
                #pragma unroll
                for (int j = 0; j < 8; j++) tmp[j] = (short)f2bf(fp[j]);
                afrag[typ][kc] = tmp;
            }
        }
    }

    // out-proj A-fragment: row 0 = ow (only wave 0 computes it)
    bf16x8 pfrag[4];
    #pragma unroll
    for (int kc = 0; kc < 4; kc++) {
        bf16x8 tmp;
        #pragma unroll
        for (int j = 0; j < 8; j++)
            tmp[j] = (l15 == 0) ? (short)f2bf(P[OFF_DOW + n * DD + 32 * kc + 8 * quad + j]) : (short)0;
        pfrag[kc] = tmp;
    }

    f32x4 bias4[4];
    #pragma unroll
    for (int typ = 0; typ < 4; typ++) {
        int base = n * G4 + typ * 128 + 16 * w + 4 * quad;
        f32x4 b1 = *(const f32x4*)&P[OFF_DBIH + base];
        f32x4 b2 = *(const f32x4*)&P[OFF_DBHH + base];
        bias4[typ].x = b1.x + b2.x; bias4[typ].y = b1.y + b2.y;
        bias4[typ].z = b1.z + b2.z; bias4[typ].w = b1.w + b2.w;
    }
    const float ob_r = P[OFF_DOB + n];

#define DEC_STEP(T, RB)                                                              \
    do {                                                                             \
        __syncthreads();                                                             \
        bf16x8 bh[4];                                                                \
        _Pragma("unroll")                                                            \
        for (int kc = 0; kc < 4; kc++)                                               \
            bh[kc] = *(const bf16x8*)&hS[RB][l15 * 136 + 32 * kc + 8 * quad];        \
        f32x4 acc[4], acc2[4];                                                       \
        _Pragma("unroll")                                                            \
        for (int typ = 0; typ < 4; typ++) {                                          \
            acc[typ] = bias4[typ];                                                   \
            acc2[typ].x = 0.f; acc2[typ].y = 0.f; acc2[typ].z = 0.f; acc2[typ].w = 0.f; \
        }                                                                            \
        _Pragma("unroll")                                                            \
        for (int kc = 0; kc < 2; kc++)                                               \
            _Pragma("unroll")                                                        \
            for (int typ = 0; typ < 4; typ++)                                        \
                acc[typ] = __builtin_amdgcn_mfma_f32_16x16x32_bf16(afrag[typ][kc], bh[kc], acc[typ], 0, 0, 0); \
        _Pragma("unroll")                                                            \
        for (int kc = 2; kc < 4; kc++)                                               \
            _Pragma("unroll")                                                        \
            for (int typ = 0; typ < 4; typ++)                                        \
                acc2[typ] = __builtin_amdgcn_mfma_f32_16x16x32_bf16(afrag[typ][kc], bh[kc], acc2[typ], 0, 0, 0); \
        _Pragma("unroll")                                                            \
        for (int typ = 0; typ < 4; typ++) acc[typ] = acc[typ] + acc2[typ];           \
        if (w == 0) {                                                                \
            f32x4 accP;                                                              \
            accP.x = ob_r; accP.y = ob_r; accP.z = ob_r; accP.w = ob_r;              \
            _Pragma("unroll")                                                        \
            for (int kc = 0; kc < 4; kc++)                                           \
                accP = __builtin_amdgcn_mfma_f32_16x16x32_bf16(pfrag[kc], bh[kc], accP, 0, 0, 0); \
            if ((T) > 0 && quad == 0)                                                \
                store_out(out, (long)bown * 4064 + (long)((T) - 1) * NV + n, accP[0], obf); \
        }                                                                            \
        ushort4 hw;                                                                  \
        _Pragma("unroll")                                                            \
        for (int r = 0; r < 4; r++) {                                                \
            float ii = sigmoid_f(acc[0][r]);                                         \
            float ff = sigmoid_f(acc[1][r]);                                         \
            float g2 = tanh_f(acc[2][r]);                                            \
            float oo = sigmoid_f(acc[3][r]);                                         \
            float cc = ff * cst[r] + ii * g2;                                        \
            cst[r] = cc;                                                             \
            ((ushort_t*)&hw)[r] = f2bf(oo * tanh_f(cc));                             \
        }                                                                            \
        *(ushort4*)&hS[(RB) ^ 1][l15 * 136 + 16 * w + 4 * quad] = hw;                \
    } while (0)

    for (int tp = 0; tp < 64; tp++) {
        DEC_STEP(2 * tp, 0);
        DEC_STEP(2 * tp + 1, 1);
    }
#undef DEC_STEP

    // o_127 from h_127 (t=127 wrote hS[0])
    __syncthreads();
    if (w == 0) {
        f32x4 accP;
        accP.x = ob_r; accP.y = ob_r; accP.z = ob_r; accP.w = ob_r;
        #pragma unroll
        for (int kc = 0; kc < 4; kc++) {
            bf16x8 bh = *(const bf16x8*)&hS[0][l15 * 136 + 32 * kc + 8 * quad];
            accP = __builtin_amdgcn_mfma_f32_16x16x32_bf16(pfrag[kc], bh, accP, 0, 0, 0);
        }
        if (quad == 0)
            store_out(out, 520192 + (long)bown * NV + n, accP[0], obf);
    }
}

extern "C" void kernel_launch(void* const* d_in, const int* in_sizes, int n_in,
                              void* d_out, int out_size, void* d_ws, size_t ws_size,
                              hipStream_t stream) {
    char* ws = (char*)d_ws;
    float*    P    = (float*)(ws + 0);              // ~595 KB
    float*    Xc   = (float*)(ws + (1u << 20));     // 2 MB
    float*    C    = (float*)(ws + (3u << 20));     // 2 MB
    float*    qb   = (float*)(ws + (5u << 20));
    float*    kb   = (float*)(ws + (7u << 20));
    float*    vb   = (float*)(ws + (9u << 20));
    float*    Cst  = (float*)(ws + (11u << 20));

    Ptr19 a;
    for (int i = 0; i < 19; i++) a.p[i] = d_in[i];

    prep_kernel<<<842, 256, 0, stream>>>(a, P, Xc);
    enc_kernel<<<dim3(8, 32), 512, 0, stream>>>(Xc, d_in[2], P, C);
    qkv_kernel<<<dim3(128, 3), 256, 0, stream>>>(C, P, qb, kb, vb);
    attn_kernel<<<128, 256, 0, stream>>>(qb, kb, vb, C, P, Cst, d_out);
    dec_kernel<<<dim3(8, 32), 512, 0, stream>>>(Cst, d_in[10], d_in[12], d_in[14], P, d_out);
}

// Round 12
// 427.274 us; speedup vs baseline: 1.0495x; 1.0495x over previous
//
#include <hip/hip_runtime.h>
#include <hip/hip_bf16.h>

typedef unsigned short ushort_t;
typedef unsigned int uint_t;

#define DD   128
#define G4   512
#define BT   16
#define NB   128
#define NV   32

// param block offsets (floats), each section 256-aligned so prep blocks map 1:1 to sources
#define OFF_WIH   0
#define OFF_EB    16384
#define OFF_PW    32768
#define OFF_PB    36864
#define OFF_INW   37120
#define OFF_INB   86272
#define OFF_OUTW  86784
#define OFF_OUTB  103168
#define OFF_IHB   103424
#define OFF_ICB   107520
#define OFF_DBIH  111616
#define OFF_DBHH  128000
#define OFF_DOW   144384
#define OFF_DOB   148480
#define P_TOTAL   148736   // = 581 * 256
// dtype flags stashed in PB-section padding: [32]=X, [33]=eWhh, [34]=iHw, [35]=iCw, [36]=dWhh
#define OFF_FLAGS (OFF_PB + 32)

typedef __attribute__((ext_vector_type(8))) short bf16x8;
typedef __attribute__((ext_vector_type(4))) float f32x4;

__device__ __forceinline__ float bf2f(ushort_t u) {
    union { uint_t i; float f; } x; x.i = ((uint_t)u) << 16; return x.f;
}
__device__ __forceinline__ ushort_t f2bf(float f) {
    __hip_bfloat16 h = __float2bfloat16(f);   // RNE
    return *(ushort_t*)&h;
}
__device__ __forceinline__ uint_t f2u(float f) {
    union { float f; uint_t i; } x; x.f = f; return x.i;
}
__device__ __forceinline__ float u2f(uint_t u) {
    union { uint_t i; float f; } x; x.i = u; return x.f;
}
__device__ __forceinline__ float sigmoid_f(float x) {
    return __builtin_amdgcn_rcpf(1.f + __expf(-x));
}
__device__ __forceinline__ float tanh_f(float x) {
    float e = __expf(2.f * x);
    return 1.f - 2.f * __builtin_amdgcn_rcpf(e + 1.f);
}
__device__ __forceinline__ float swz_bcast_l15(float v) {
    // BitMode and=0x0F: new_lane = lane & 15 (within each 32-lane half)
    return u2f((uint_t)__builtin_amdgcn_ds_swizzle((int)f2u(v), 0x000F));
}
__device__ __forceinline__ void store_out(void* out, long idx, float v, int bf) {
    if (bf) ((ushort_t*)out)[idx] = f2bf(v);
    else    ((float*)out)[idx]    = v;
}
// per-wave dtype probe: 1 if data looks bf16 when read as ushort
__device__ __forceinline__ int wave_probe(const void* p, int elems) {
    int cap = elems < 2048 ? elems : 2048;
    int lane = threadIdx.x & 63;
    const ushort_t* u = (const ushort_t*)p;
    int cnt = 0, tot = 0;
    for (int j = lane; j < cap; j += 64) {
        ushort_t x = u[j];
        float af = fabsf(bf2f(x));
        tot++;
        if (x == 0 || (af > 1e-7f && af < 100.f)) cnt++;
    }
    #pragma unroll
    for (int off = 32; off >= 1; off >>= 1) {
        cnt += __shfl_xor(cnt, off);
        tot += __shfl_xor(tot, off);
    }
    return (cnt * 10 >= tot * 9) ? 1 : 0;
}

struct Ptr19 { const void* p[19]; };

// ---------------- prep: params (581) + X transpose (256) + dtype flags (5) ----------------
__global__ __launch_bounds__(256) void prep_kernel(Ptr19 a, float* __restrict__ P,
                                                   float* __restrict__ Xc) {
    __shared__ float tile[32][65];
    if (blockIdx.x < 581) {
        int base = blockIdx.x * 256;
        int src, o0, size;
        if      (base < OFF_EB)   { src = 1;  o0 = base - OFF_WIH;  size = 16384; }
        else if (base < OFF_PW)   { src = 3;  o0 = base - OFF_EB;   size = 16384; }
        else if (base < OFF_PB)   { src = 4;  o0 = base - OFF_PW;   size = 4096;  }
        else if (base < OFF_INW)  { src = 5;  o0 = base - OFF_PB;   size = 32;    }
        else if (base < OFF_INB)  { src = 6;  o0 = base - OFF_INW;  size = 49152; }
        else if (base < OFF_OUTW) { src = 7;  o0 = base - OFF_INB;  size = 384;   }
        else if (base < OFF_OUTB) { src = 8;  o0 = base - OFF_OUTW; size = 16384; }
        else if (base < OFF_IHB)  { src = 9;  o0 = base - OFF_OUTB; size = 128;   }
        else if (base < OFF_ICB)  { src = 11; o0 = base - OFF_IHB;  size = 4096;  }
        else if (base < OFF_DBIH) { src = 13; o0 = base - OFF_ICB;  size = 4096;  }
        else if (base < OFF_DBHH) { src = 15; o0 = base - OFF_DBIH; size = 16384; }
        else if (base < OFF_DOW)  { src = 16; o0 = base - OFF_DBHH; size = 16384; }
        else if (base < OFF_DOB)  { src = 17; o0 = base - OFF_DOW;  size = 4096;  }
        else                      { src = 18; o0 = base - OFF_DOB;  size = 32;    }
        int bf = wave_probe(a.p[src], size);
        int off = o0 + (int)threadIdx.x;
        if (off < size)
            P[base + threadIdx.x] = bf ? bf2f(((const ushort_t*)a.p[src])[off])
                                       : ((const float*)a.p[src])[off];
    } else if (blockIdx.x < 837) {
        int bf = wave_probe(a.p[0], 2048);
        int idx2 = blockIdx.x - 581;
        int bt = (idx2 & 3) * 32, tn0 = (idx2 >> 2) * 64;
        const void* src = a.p[0];
        int tx = threadIdx.x & 63, ty = threadIdx.x >> 6;
        #pragma unroll
        for (int k = 0; k < 8; k++) {
            int row = ty * 8 + k;
            int idx = (bt + row) * 4096 + tn0 + tx;
            tile[row][tx] = bf ? bf2f(((const ushort_t*)src)[idx]) : ((const float*)src)[idx];
        }
        __syncthreads();
        int bx = threadIdx.x & 31, tyy = threadIdx.x >> 5;
        #pragma unroll
        for (int k = 0; k < 8; k++) {
            int tn = tn0 + tyy * 8 + k;
            int t = tn >> 5, nn = tn & 31;
            Xc[t * 4096 + nn * 128 + bt + bx] = tile[bx][tyy * 8 + k];
        }
    } else {
        int which = blockIdx.x - 837;            // 0..4
        int src = (which == 0) ? 0 : (which == 1) ? 2 : (which == 2) ? 10
                : (which == 3) ? 12 : 14;
        int flag = wave_probe(a.p[src], 2048);
        if (threadIdx.x == 0) P[OFF_FLAGS + which] = (float)flag;
    }
}

// ===================== encoder: operand-swapped MFMA recurrence (r10 structure) =====================
// D[g-row][b-col]: thread owns (b = l15, d = 16w + 4quad + r, r=0..3).
__global__ __launch_bounds__(512, 2) void enc_kernel(
    const float* __restrict__ Xc, const void* __restrict__ Wraw,
    const float* __restrict__ P, float* __restrict__ Cout)
{
    const int n = blockIdx.y, b0 = blockIdx.x * BT;
    const int tid = threadIdx.x;
    const int w = tid >> 6, lane = tid & 63;
    const int l15 = lane & 15, quad = lane >> 4;
    const int wbf = P[OFF_FLAGS + 1] > 0.5f;
    const int bown = b0 + l15;

    __shared__ alignas(16) ushort_t hS[2][16 * 136];
    for (int i = tid; i < 16 * 136; i += 512) hS[0][i] = 0;

    // A-fragments (weights): lane holds W[g = typ*128 + 16w + l15][k = 32kc+8quad+j]
    bf16x8 afrag[4][4];
    #pragma unroll
    for (int typ = 0; typ < 4; typ++) {
        const int g = typ * 128 + 16 * w + l15;
        #pragma unroll
        for (int kc = 0; kc < 4; kc++) {
            const int base = (n * G4 + g) * DD + 32 * kc + 8 * quad;
            if (wbf) {
                afrag[typ][kc] = *(const bf16x8*)((const ushort_t*)Wraw + base);
            } else {
                const float* fp = (const float*)Wraw + base;
                bf16x8 tmp;
                #pragma unroll
                for (int j = 0; j < 8; j++) tmp[j] = (short)f2bf(fp[j]);
                afrag[typ][kc] = tmp;
            }
        }
    }

    // pool A-fragment: rows 0 and 8 carry pw (so both 32-lane halves get s)
    bf16x8 pfrag[4];
    #pragma unroll
    for (int kc = 0; kc < 4; kc++) {
        bf16x8 tmp;
        #pragma unroll
        for (int j = 0; j < 8; j++)
            tmp[j] = (l15 == 0 || l15 == 8)
                   ? (short)f2bf(P[OFF_PW + n * DD + 32 * kc + 8 * quad + j]) : (short)0;
        pfrag[kc] = tmp;
    }

    f32x4 bias4[4], wih4[4];
    #pragma unroll
    for (int typ = 0; typ < 4; typ++) {
        int base = n * G4 + typ * 128 + 16 * w + 4 * quad;
        bias4[typ] = *(const f32x4*)&P[OFF_EB + base];
        wih4[typ]  = *(const f32x4*)&P[OFF_WIH + base];
    }
    const float pb_r = P[OFF_PB + n];

    float cst[4], hprev[4], Cacc[4], lR = 0.f;
    #pragma unroll
    for (int r = 0; r < 4; r++) { cst[r] = 0.f; hprev[r] = 0.f; Cacc[r] = 0.f; }

    float xq = Xc[n * 128 + bown];   // t = 0

#define ENC_STEP(T, RB)                                                              \
    do {                                                                             \
        __syncthreads();                                                             \
        bf16x8 bh[4];                                                                \
        _Pragma("unroll")                                                            \
        for (int kc = 0; kc < 4; kc++)                                               \
            bh[kc] = *(const bf16x8*)&hS[RB][l15 * 136 + 32 * kc + 8 * quad];        \
        f32x4 acc[4], accP;                                                          \
        _Pragma("unroll")                                                            \
        for (int typ = 0; typ < 4; typ++) {                                          \
            f32x4 a;                                                                 \
            a.x = bias4[typ].x + xq * wih4[typ].x;                                   \
            a.y = bias4[typ].y + xq * wih4[typ].y;                                   \
            a.z = bias4[typ].z + xq * wih4[typ].z;                                   \
            a.w = bias4[typ].w + xq * wih4[typ].w;                                   \
            acc[typ] = a;                                                            \
        }                                                                            \
        accP.x = pb_r; accP.y = pb_r; accP.z = pb_r; accP.w = pb_r;                  \
        if ((T) < 126) xq = Xc[((T) + 1) * 4096 + n * 128 + bown];                   \
        _Pragma("unroll")                                                            \
        for (int kc = 0; kc < 4; kc++) {                                             \
            accP = __builtin_amdgcn_mfma_f32_16x16x32_bf16(pfrag[kc], bh[kc], accP, 0, 0, 0); \
            _Pragma("unroll")                                                        \
            for (int typ = 0; typ < 4; typ++)                                        \
                acc[typ] = __builtin_amdgcn_mfma_f32_16x16x32_bf16(afrag[typ][kc], bh[kc], acc[typ], 0, 0, 0); \
        }                                                                            \
        if ((T) > 0) {                                                               \
            float e = __expf(swz_bcast_l15(accP[0]));                                \
            lR += e;                                                                 \
            _Pragma("unroll")                                                        \
            for (int r = 0; r < 4; r++) Cacc[r] = fmaf(e, hprev[r], Cacc[r]);        \
        }                                                                            \
        ushort4 hw;                                                                  \
        _Pragma("unroll")                                                            \
        for (int r = 0; r < 4; r++) {                                                \
            float ii = sigmoid_f(acc[0][r]);                                         \
            float ff = sigmoid_f(acc[1][r]);                                         \
            float g2 = tanh_f(acc[2][r]);                                            \
            float oo = sigmoid_f(acc[3][r]);                                         \
            float cc = ff * cst[r] + ii * g2;                                        \
            cst[r] = cc;                                                             \
            float hh = oo * tanh_f(cc);                                              \
            hprev[r] = hh;                                                           \
            ((ushort_t*)&hw)[r] = f2bf(hh);                                          \
        }                                                                            \
        *(ushort4*)&hS[(RB) ^ 1][l15 * 136 + 16 * w + 4 * quad] = hw;                \
    } while (0)

    for (int tp = 0; tp < 63; tp++) {
        ENC_STEP(2 * tp, 0);
        ENC_STEP(2 * tp + 1, 1);
    }
    ENC_STEP(126, 0);
#undef ENC_STEP

    // final fold: score of h_126 (in hS[1])
    __syncthreads();
    {
        f32x4 accP;
        accP.x = pb_r; accP.y = pb_r; accP.z = pb_r; accP.w = pb_r;
        #pragma unroll
        for (int kc = 0; kc < 4; kc++) {
            bf16x8 bh = *(const bf16x8*)&hS[1][l15 * 136 + 32 * kc + 8 * quad];
            accP = __builtin_amdgcn_mfma_f32_16x16x32_bf16(pfrag[kc], bh, accP, 0, 0, 0);
        }
        float e = __expf(swz_bcast_l15(accP[0]));
        lR += e;
        #pragma unroll
        for (int r = 0; r < 4; r++) Cacc[r] = fmaf(e, hprev[r], Cacc[r]);
    }
    float inv = 1.f / lR;
    f32x4 cv;
    cv.x = Cacc[0] * inv; cv.y = Cacc[1] * inv; cv.z = Cacc[2] * inv; cv.w = Cacc[3] * inv;
    *(f32x4*)&Cout[bown * (NV * DD) + n * DD + 16 * w + 4 * quad] = cv;
}

// ---------------- QKV projection ----------------
__global__ __launch_bounds__(256) void qkv_kernel(
    const float* __restrict__ C, const float* __restrict__ P,
    float* __restrict__ q, float* __restrict__ k, float* __restrict__ v)
{
    int b = blockIdx.x, p = blockIdx.y, tid = threadIdx.x;
    int j = tid & 127, half = tid >> 7;
    __shared__ float Cb[NV * DD];
    for (int i = tid; i < NV * DD; i += 256) Cb[i] = C[b * (NV * DD) + i];
    __syncthreads();

    const float* wrow = P + OFF_INW + (p * DD + j) * DD;
    float bias = P[OFF_INB + p * DD + j];
    float acc[16];
    #pragma unroll
    for (int nn = 0; nn < 16; nn++) acc[nn] = bias;

    for (int dc = 0; dc < DD; dc += 8) {
        float4 w0 = *(const float4*)&wrow[dc];
        float4 w1 = *(const float4*)&wrow[dc + 4];
        #pragma unroll
        for (int nn = 0; nn < 16; nn++) {
            const float* cb = &Cb[(half * 16 + nn) * DD + dc];
            float4 c0 = *(float4*)&cb[0];
            float4 c1 = *(float4*)&cb[4];
            acc[nn] += c0.x * w0.x + c0.y * w0.y + c0.z * w0.z + c0.w * w0.w
                     + c1.x * w1.x + c1.y * w1.y + c1.z * w1.z + c1.w * w1.w;
        }
    }
    float* dst = (p == 0) ? q : (p == 1) ? k : v;
    for (int nn = 0; nn < 16; nn++)
        dst[b * (NV * DD) + (half * 16 + nn) * DD + j] = acc[nn];
}

// ---------------- cross-attention + out-proj + residual, split by query-half ----------------
// grid (128, 2), 128 threads. Block (b, half) owns queries nn in [16*half, 16*half+16).
__global__ __launch_bounds__(128) void attn_kernel(
    const float* __restrict__ q, const float* __restrict__ k, const float* __restrict__ v,
    const float* __restrict__ C, const float* __restrict__ P,
    float* __restrict__ Cstar, void* __restrict__ dout)
{
    int b = blockIdx.x, half = blockIdx.y, tid = threadIdx.x;
    int obf = P[OFF_FLAGS + 0] > 0.5f;
    int n0 = half * 16;
    __shared__ float Qs[16 * DD], Ks[NV * DD], Vs[NV * DD];
    float* Os = Ks;   // reused after last Ks read (sync-separated)
    for (int i = tid; i < 16 * DD; i += 128) Qs[i] = q[b * (NV * DD) + n0 * DD + i];
    __syncthreads();

    int hh = tid >> 4, qi = tid & 15;   // 8 heads x 16 queries
    float qreg[16];
    #pragma unroll
    for (int u = 0; u < 4; u++) {
        float4 t4 = *(float4*)&Qs[qi * DD + hh * 16 + 4 * u];
        qreg[4*u] = t4.x; qreg[4*u+1] = t4.y; qreg[4*u+2] = t4.z; qreg[4*u+3] = t4.w;
    }

    float Oacc[16];
    #pragma unroll
    for (int u = 0; u < 16; u++) Oacc[u] = 0.f;
    float wsum = 0.f;
    int tmax = (b < 5) ? b : 5;

    for (int tau = 1; tau <= tmax; tau++) {
        __syncthreads();
        for (int i = tid; i < NV * DD; i += 128) {
            Ks[i] = k[(b - tau) * (NV * DD) + i];
            Vs[i] = v[(b - tau) * (NV * DD) + i];
        }
        __syncthreads();

        float s[NV];
        #pragma unroll
        for (int kk = 0; kk < NV; kk++) {
            float a = 0.f;
            #pragma unroll
            for (int u = 0; u < 4; u++) {
                float4 kv = *(float4*)&Ks[kk * DD + hh * 16 + 4 * u];
                a += qreg[4*u] * kv.x + qreg[4*u+1] * kv.y
                   + qreg[4*u+2] * kv.z + qreg[4*u+3] * kv.w;
            }
            s[kk] = a * 0.25f;
        }
        float mm = s[0];
        #pragma unroll
        for (int kk = 1; kk < NV; kk++) mm = fmaxf(mm, s[kk]);
        float ssum = 0.f;
        #pragma unroll
        for (int kk = 0; kk < NV; kk++) { s[kk] = __expf(s[kk] - mm); ssum += s[kk]; }
        float wdk = __expf(-0.7f * (float)(tau - 1));
        wsum += wdk;
        float wr = wdk / ssum;
        #pragma unroll
        for (int u = 0; u < 4; u++) {
            float ax = 0.f, ay = 0.f, az = 0.f, aw = 0.f;
            #pragma unroll
            for (int kk = 0; kk < NV; kk++) {
                float4 vv = *(float4*)&Vs[kk * DD + hh * 16 + 4 * u];
                ax += s[kk] * vv.x; ay += s[kk] * vv.y;
                az += s[kk] * vv.z; aw += s[kk] * vv.w;
            }
            Oacc[4*u] += wr * ax; Oacc[4*u+1] += wr * ay;
            Oacc[4*u+2] += wr * az; Oacc[4*u+3] += wr * aw;
        }
    }

    __syncthreads();
    float winv = (b > 0) ? 1.f / wsum : 0.f;
    #pragma unroll
    for (int u = 0; u < 16; u++)
        Os[qi * DD + hh * 16 + u] = Oacc[u] * winv;   // Os rows = local queries 0..15
    __syncthreads();

    int j = tid;   // 0..127 output column
    const float* wrow = P + OFF_OUTW + j * DD;
    float obias = P[OFF_OUTB + j];
    for (int nn = 0; nn < 16; nn++) {
        float a = (b > 0) ? obias : 0.f;
        for (int dc = 0; dc < DD; dc += 8) {
            float4 w0 = *(const float4*)&wrow[dc];
            float4 w1 = *(const float4*)&wrow[dc + 4];
            float4 o0 = *(float4*)&Os[nn * DD + dc];
            float4 o1 = *(float4*)&Os[nn * DD + dc + 4];
            a += o0.x*w0.x + o0.y*w0.y + o0.z*w0.z + o0.w*w0.w
               + o1.x*w1.x + o1.y*w1.y + o1.z*w1.z + o1.w*w1.w;
        }
        int nng = n0 + nn;
        float cs = C[b * (NV * DD) + nng * DD + j] + a;
        Cstar[b * (NV * DD) + nng * DD + j] = cs;
        store_out(dout, 524288 + b * (NV * DD) + nng * DD + j, cs, obf);
    }
}

// ===================== decoder: fused init + operand-swapped MFMA recurrence (r10 structure) =====================
__global__ __launch_bounds__(512, 2) void dec_kernel(
    const float* __restrict__ Cstar,
    const void* __restrict__ iHw, const void* __restrict__ iCw,
    const void* __restrict__ Wraw,
    const float* __restrict__ P, void* __restrict__ out)
{
    const int n = blockIdx.y, b0 = blockIdx.x * BT;
    const int tid = threadIdx.x;
    const int w = tid >> 6, lane = tid & 63;
    const int l15 = lane & 15, quad = lane >> 4;
    const int obf = P[OFF_FLAGS + 0] > 0.5f;
    const int hbf = P[OFF_FLAGS + 2] > 0.5f;
    const int cbf = P[OFF_FLAGS + 3] > 0.5f;
    const int wbf = P[OFF_FLAGS + 4] > 0.5f;
    const int bown = b0 + l15;

    __shared__ alignas(16) ushort_t hS[2][16 * 136];

    // ---- fused init: D[e-row][b-col] = Cst·W^T + b ----
    bf16x8 cstB[4];
    #pragma unroll
    for (int kc = 0; kc < 4; kc++) {
        const float* cp = &Cstar[bown * (NV * DD) + n * DD + 32 * kc + 8 * quad];
        f32x4 c0v = *(const f32x4*)&cp[0];
        f32x4 c1v = *(const f32x4*)&cp[4];
        bf16x8 tmp;
        tmp[0] = (short)f2bf(c0v.x); tmp[1] = (short)f2bf(c0v.y);
        tmp[2] = (short)f2bf(c0v.z); tmp[3] = (short)f2bf(c0v.w);
        tmp[4] = (short)f2bf(c1v.x); tmp[5] = (short)f2bf(c1v.y);
        tmp[6] = (short)f2bf(c1v.z); tmp[7] = (short)f2bf(c1v.w);
        cstB[kc] = tmp;
    }
    float cst[4];
    {
        f32x4 hAcc = *(const f32x4*)&P[OFF_IHB + n * DD + 16 * w + 4 * quad];
        f32x4 cAcc = *(const f32x4*)&P[OFF_ICB + n * DD + 16 * w + 4 * quad];
        #pragma unroll
        for (int kc = 0; kc < 4; kc++) {
            const int base = (n * DD + 16 * w + l15) * DD + 32 * kc + 8 * quad;
            bf16x8 wA;
            if (hbf) wA = *(const bf16x8*)((const ushort_t*)iHw + base);
            else {
                const float* fp = (const float*)iHw + base;
                #pragma unroll
                for (int j = 0; j < 8; j++) wA[j] = (short)f2bf(fp[j]);
            }
            hAcc = __builtin_amdgcn_mfma_f32_16x16x32_bf16(wA, cstB[kc], hAcc, 0, 0, 0);
            if (cbf) wA = *(const bf16x8*)((const ushort_t*)iCw + base);
            else {
                const float* fp = (const float*)iCw + base;
                #pragma unroll
                for (int j = 0; j < 8; j++) wA[j] = (short)f2bf(fp[j]);
            }
            cAcc = __builtin_amdgcn_mfma_f32_16x16x32_bf16(wA, cstB[kc], cAcc, 0, 0, 0);
        }
        ushort4 hw;
        #pragma unroll
        for (int r = 0; r < 4; r++) {
            ((ushort_t*)&hw)[r] = f2bf(tanh_f(hAcc[r]));
            cst[r] = tanh_f(cAcc[r]);
        }
        *(ushort4*)&hS[0][l15 * 136 + 16 * w + 4 * quad] = hw;
    }

    // ---- recurrence weights (A-operand) ----
    bf16x8 afrag[4][4];
    #pragma unroll
    for (int typ = 0; typ < 4; typ++) {
        const int g = typ * 128 + 16 * w + l15;
        #pragma unroll
        for (int kc = 0; kc < 4; kc++) {
            const int base = (n * G4 + g) * DD + 32 * kc + 8 * quad;
            if (wbf) {
                afrag[typ][kc] = *(const bf16x8*)((const ushort_t*)Wraw + base);
            } else {
                const float* fp = (const float*)Wraw + base;
                bf16x8 tmp;
                #pragma unroll
                for (int j = 0; j < 8; j++) tmp[j] = (short)f2bf(fp[j]);
                afrag[typ][kc] = tmp;
            }
        }
    }

    // out-proj A-fragment: row 0 = ow (only wave 0 computes it)
    bf16x8 pfrag[4];
    #pragma unroll
    for (int kc = 0; kc < 4; kc++) {
        bf16x8 tmp;
        #pragma unroll
        for (int j = 0; j < 8; j++)
            tmp[j] = (l15 == 0) ? (short)f2bf(P[OFF_DOW + n * DD + 32 * kc + 8 * quad + j]) : (short)0;
        pfrag[kc] = tmp;
    }

    f32x4 bias4[4];
    #pragma unroll
    for (int typ = 0; typ < 4; typ++) {
        int base = n * G4 + typ * 128 + 16 * w + 4 * quad;
        f32x4 b1 = *(const f32x4*)&P[OFF_DBIH + base];
        f32x4 b2 = *(const f32x4*)&P[OFF_DBHH + base];
        bias4[typ].x = b1.x + b2.x; bias4[typ].y = b1.y + b2.y;
        bias4[typ].z = b1.z + b2.z; bias4[typ].w = b1.w + b2.w;
    }
    const float ob_r = P[OFF_DOB + n];

#define DEC_STEP(T, RB)                                                              \
    do {                                                                             \
        __syncthreads();                                                             \
        bf16x8 bh[4];                                                                \
        _Pragma("unroll")                                                            \
        for (int kc = 0; kc < 4; kc++)                                               \
            bh[kc] = *(const bf16x8*)&hS[RB][l15 * 136 + 32 * kc + 8 * quad];        \
        f32x4 acc[4];                                                                \
        _Pragma("unroll")                                                            \
        for (int typ = 0; typ < 4; typ++) acc[typ] = bias4[typ];                     \
        _Pragma("unroll")                                                            \
        for (int kc = 0; kc < 4; kc++)                                               \
            _Pragma("unroll")                                                        \
            for (int typ = 0; typ < 4; typ++)                                        \
                acc[typ] = __builtin_amdgcn_mfma_f32_16x16x32_bf16(afrag[typ][kc], bh[kc], acc[typ], 0, 0, 0); \
        if (w == 0) {                                                                \
            f32x4 accP;                                                              \
            accP.x = ob_r; accP.y = ob_r; accP.z = ob_r; accP.w = ob_r;              \
            _Pragma("unroll")                                                        \
            for (int kc = 0; kc < 4; kc++)                                           \
                accP = __builtin_amdgcn_mfma_f32_16x16x32_bf16(pfrag[kc], bh[kc], accP, 0, 0, 0); \
            if ((T) > 0 && quad == 0)                                                \
                store_out(out, (long)bown * 4064 + (long)((T) - 1) * NV + n, accP[0], obf); \
        }                                                                            \
        ushort4 hw;                                                                  \
        _Pragma("unroll")                                                            \
        for (int r = 0; r < 4; r++) {                                                \
            float ii = sigmoid_f(acc[0][r]);                                         \
            float ff = sigmoid_f(acc[1][r]);                                         \
            float g2 = tanh_f(acc[2][r]);                                            \
            float oo = sigmoid_f(acc[3][r]);                                         \
            float cc = ff * cst[r] + ii * g2;                                        \
            cst[r] = cc;                                                             \
            ((ushort_t*)&hw)[r] = f2bf(oo * tanh_f(cc));                             \
        }                                                                            \
        *(ushort4*)&hS[(RB) ^ 1][l15 * 136 + 16 * w + 4 * quad] = hw;                \
    } while (0)

    for (int tp = 0; tp < 64; tp++) {
        DEC_STEP(2 * tp, 0);
        DEC_STEP(2 * tp + 1, 1);
    }
#undef DEC_STEP

    // o_127 from h_127 (t=127 wrote hS[0])
    __syncthreads();
    if (w == 0) {
        f32x4 accP;
        accP.x = ob_r; accP.y = ob_r; accP.z = ob_r; accP.w = ob_r;
        #pragma unroll
        for (int kc = 0; kc < 4; kc++) {
            bf16x8 bh = *(const bf16x8*)&hS[0][l15 * 136 + 32 * kc + 8 * quad];
            accP = __builtin_amdgcn_mfma_f32_16x16x32_bf16(pfrag[kc], bh, accP, 0, 0, 0);
        }
        if (quad == 0)
            store_out(out, 520192 + (long)bown * NV + n, accP[0], obf);
    }
}

extern "C" void kernel_launch(void* const* d_in, const int* in_sizes, int n_in,
                              void* d_out, int out_size, void* d_ws, size_t ws_size,
                              hipStream_t stream) {
    char* ws = (char*)d_ws;
    float*    P    = (float*)(ws + 0);              // ~595 KB
    float*    Xc   = (float*)(ws + (1u << 20));     // 2 MB
    float*    C    = (float*)(ws + (3u << 20));     // 2 MB
    float*    qb   = (float*)(ws + (5u << 20));
    float*    kb   = (float*)(ws + (7u << 20));
    float*    vb   = (float*)(ws + (9u << 20));
    float*    Cst  = (float*)(ws + (11u << 20));

    Ptr19 a;
    for (int i = 0; i < 19; i++) a.p[i] = d_in[i];

    prep_kernel<<<842, 256, 0, stream>>>(a, P, Xc);
    enc_kernel<<<dim3(8, 32), 512, 0, stream>>>(Xc, d_in[2], P, C);
    qkv_kernel<<<dim3(128, 3), 256, 0, stream>>>(C, P, qb, kb, vb);
    attn_kernel<<<dim3(128, 2), 128, 0, stream>>>(qb, kb, vb, C, P, Cst, d_out);
    dec_kernel<<<dim3(8, 32), 512, 0, stream>>>(Cst, d_in[10], d_in[12], d_in[14], P, d_out);
}